// Round 1
// 555.672 us; speedup vs baseline: 1.0340x; 1.0340x over previous
//
#include <hip/hip_runtime.h>
#include <hip/hip_bf16.h>
#include <math.h>

#define NF 6
#define QL 4096
#define SCALE 0.125f
#define EPSLN 1e-5f

typedef __bf16 bf16x8 __attribute__((ext_vector_type(8)));
typedef __bf16 bf16x4 __attribute__((ext_vector_type(4)));
typedef float  f32x4  __attribute__((ext_vector_type(4)));

// ---- workspace layout (bytes) ----
#define OFF_WQT   0u
#define OFF_WKT   131072u
#define OFF_WVT   262144u
#define OFF_WPT   393216u
#define OFF_W1T   524288u     // 512x256 packed bf16
#define OFF_W2T   786432u     // 256x512 packed bf16
#define OFF_QH    1048576u    // 24576 x 256 bf16
#define OFF_ATT   13631488u   // 4096 x 4 x 48 f32
#define OFF_OPART 16777216u   // 6 x 4096 x 256 f32

__device__ __forceinline__ unsigned short f2bf(float x) {
  union { float f; unsigned u; } v; v.f = x;
  unsigned r = v.u + 0x7FFFu + ((v.u >> 16) & 1u);
  return (unsigned short)(r >> 16);
}
__device__ __forceinline__ unsigned long long pack4bf(float a, float b, float c, float d) {
  unsigned d0 = (unsigned)f2bf(a) | ((unsigned)f2bf(b) << 16);
  unsigned d1 = (unsigned)f2bf(c) | ((unsigned)f2bf(d) << 16);
  return (unsigned long long)d0 | ((unsigned long long)d1 << 32);
}

// ===== prep: W[K][N] f32 -> MFMA-fragment-packed bf16 =====================
// layout: out[(ntile*KT + kt)*512 + lane*8 + j] = W[kt*32 + (lane>>4)*8 + j][ntile*16 + (lane&15)]
__global__ void __launch_bounds__(256)
prep_kernel(const float* __restrict__ wq, const float* __restrict__ wk,
            const float* __restrict__ wv, const float* __restrict__ wp,
            const float* __restrict__ w1, const float* __restrict__ w2,
            unsigned short* __restrict__ wsu16)
{
  const int blk = blockIdx.x, t = threadIdx.x;
  const float* src; unsigned short* dst; int N, KT, ntile;
  if (blk < 64) {
    int mi = blk >> 4; ntile = blk & 15; N = 256; KT = 8;
    src = (mi == 0) ? wq : (mi == 1) ? wk : (mi == 2) ? wv : wp;
    dst = wsu16 + (size_t)mi * 65536;
  } else if (blk < 96) {
    ntile = blk - 64; N = 512; KT = 8; src = w1; dst = wsu16 + OFF_W1T / 2;
  } else {
    ntile = blk - 96; N = 256; KT = 16; src = w2; dst = wsu16 + OFF_W2T / 2;
  }
  const int lane = t & 63;
  const int lr = lane & 15, quad = lane >> 4;
  const int ncol = ntile * 16 + lr;
  for (int kt = (t >> 6); kt < KT; kt += 4) {
    unsigned v8[8];
#pragma unroll
    for (int j = 0; j < 8; ++j) {
      int krow = kt * 32 + quad * 8 + j;
      v8[j] = f2bf(src[(size_t)krow * N + ncol]);
    }
    uint4 u;
    u.x = v8[0] | (v8[1] << 16); u.y = v8[2] | (v8[3] << 16);
    u.z = v8[4] | (v8[5] << 16); u.w = v8[6] | (v8[7] << 16);
    *(uint4*)(dst + ((size_t)(ntile * KT + kt) * 512 + lane * 8)) = u;
  }
}

// ===== proj-q: gather-transpose + LN + MFMA (64-px tiles) -> qh bf16 ======
__global__ void __launch_bounds__(256, 4)
projq_kernel(const float* __restrict__ src,
             const float* __restrict__ lng, const float* __restrict__ lnb,
             const unsigned short* __restrict__ wTp,
             const float* __restrict__ bias,
             unsigned short* __restrict__ qh)
{
  __shared__ __align__(16) unsigned short s_x[64 * 264];
  const int t = threadIdx.x, blk = blockIdx.x;
  const int n = blk >> 6, qp0 = (blk & 63) << 6;

  // stage + transpose raw as bf16
  {
    const int l16 = t & 15, dg = t >> 4;
    for (int it = 0; it < 16; ++it) {
      int dcol = it * 16 + dg;
      float4 x = *(const float4*)(src + ((size_t)(n * 256 + dcol)) * 4096 + qp0 + l16 * 4);
      s_x[(l16 * 4 + 0) * 264 + dcol] = f2bf(x.x);
      s_x[(l16 * 4 + 1) * 264 + dcol] = f2bf(x.y);
      s_x[(l16 * 4 + 2) * 264 + dcol] = f2bf(x.z);
      s_x[(l16 * 4 + 3) * 264 + dcol] = f2bf(x.w);
    }
  }
  __syncthreads();
  // two-pass LN (4 threads/row)
  {
    const int row = t >> 2, sl = t & 3;
    float s = 0.f, s2 = 0.f;
#pragma unroll
    for (int i = 0; i < 8; ++i) {
      bf16x8 xv = *(const bf16x8*)(s_x + row * 264 + (i * 4 + sl) * 8);
#pragma unroll
      for (int j = 0; j < 8; ++j) { float f = (float)xv[j]; s += f; s2 += f * f; }
    }
    s += __shfl_xor(s, 1, 64);  s += __shfl_xor(s, 2, 64);
    s2 += __shfl_xor(s2, 1, 64); s2 += __shfl_xor(s2, 2, 64);
    float mu = s * (1.f / 256.f);
    float var = s2 * (1.f / 256.f) - mu * mu;
    float istd = rsqrtf(var + EPSLN);
#pragma unroll
    for (int i = 0; i < 8; ++i) {
      int c = (i * 4 + sl) * 8;
      bf16x8 xv = *(const bf16x8*)(s_x + row * 264 + c);
      f32x4 ga = *(const f32x4*)(lng + c), gb = *(const f32x4*)(lng + c + 4);
      f32x4 ba = *(const f32x4*)(lnb + c), bb = *(const f32x4*)(lnb + c + 4);
      uint4 u;
      u.x = (unsigned)f2bf(((float)xv[0] - mu) * istd * ga[0] + ba[0]) |
            ((unsigned)f2bf(((float)xv[1] - mu) * istd * ga[1] + ba[1]) << 16);
      u.y = (unsigned)f2bf(((float)xv[2] - mu) * istd * ga[2] + ba[2]) |
            ((unsigned)f2bf(((float)xv[3] - mu) * istd * ga[3] + ba[3]) << 16);
      u.z = (unsigned)f2bf(((float)xv[4] - mu) * istd * gb[0] + bb[0]) |
            ((unsigned)f2bf(((float)xv[5] - mu) * istd * gb[1] + bb[1]) << 16);
      u.w = (unsigned)f2bf(((float)xv[6] - mu) * istd * gb[2] + bb[2]) |
            ((unsigned)f2bf(((float)xv[7] - mu) * istd * gb[3] + bb[3]) << 16);
      *(uint4*)(s_x + row * 264 + c) = u;
    }
  }
  __syncthreads();

  // MFMA: M=64, wave covers N-slice w*64
  const int w = t >> 6, lane = t & 63, lr = lane & 15, quad = lane >> 4;
  f32x4 acc[4][4];
  {
    f32x4 z = {0.f, 0.f, 0.f, 0.f};
#pragma unroll
    for (int a = 0; a < 4; ++a)
#pragma unroll
      for (int b = 0; b < 4; ++b) acc[a][b] = z;
  }
  for (int kt = 0; kt < 8; ++kt) {
    bf16x8 xf[4];
#pragma unroll
    for (int mt = 0; mt < 4; ++mt)
      xf[mt] = *(const bf16x8*)(s_x + (mt * 16 + lr) * 264 + kt * 32 + quad * 8);
#pragma unroll
    for (int nt = 0; nt < 4; ++nt) {
      bf16x8 wf = *(const bf16x8*)(wTp + ((size_t)((w * 4 + nt) * 8 + kt) * 512 + lane * 8));
#pragma unroll
      for (int mt = 0; mt < 4; ++mt)
        acc[nt][mt] = __builtin_amdgcn_mfma_f32_16x16x32_bf16(wf, xf[mt], acc[nt][mt], 0, 0, 0);
    }
  }
  __syncthreads();
#pragma unroll
  for (int nt = 0; nt < 4; ++nt) {
    int n0 = w * 64 + nt * 16 + quad * 4;
    f32x4 bb = *(const f32x4*)(bias + n0);
#pragma unroll
    for (int mt = 0; mt < 4; ++mt) {
      int m = mt * 16 + lr;
      f32x4 a = acc[nt][mt];
      *(unsigned long long*)(s_x + m * 264 + n0) =
          pack4bf(a[0] + bb[0], a[1] + bb[1], a[2] + bb[2], a[3] + bb[3]);
    }
  }
  __syncthreads();
  // dump 64 rows x 512B contiguous
  unsigned char* ob = (unsigned char*)qh + ((size_t)n * QL + qp0) * 512;
#pragma unroll
  for (int i = 0; i < 8; ++i) {
    int lin = i * 4096 + t * 16;
    int r = lin >> 9, off = lin & 511;
    *(uint4*)(ob + lin) = *(const uint4*)((const unsigned char*)s_x + r * 528 + off);
  }
}

// ===== fused proj k/v: register-staged LN + MFMA + score / softmax+PV =====
__global__ void __launch_bounds__(256, 4)
projkv_kernel(const float* __restrict__ src,
              const float* __restrict__ lng, const float* __restrict__ lnb,
              const unsigned short* __restrict__ wTp,
              const float* __restrict__ bias,
              const unsigned short* __restrict__ qh,
              float* __restrict__ attg,
              const int* __restrict__ mask,
              float* __restrict__ opart,
              int kind)  // 0 = K (scores), 1 = V (softmax + PV partials)
{
  __shared__ __align__(16) unsigned short s_x[32 * 264];
  __shared__ __align__(16) float s_att[16 * 48];
  const int t = threadIdx.x, blk = blockIdx.x;
  const int n = blk >> 10, qp0 = (blk & 1023) << 2;
  const int w = t >> 6, lane = t & 63;

  // register-staged two-pass LN: 8 threads/row, 32 f32 each, direct to VGPR
  {
    const int row = t >> 3, sl = t & 7;
    const float* gr = src + ((size_t)blk * 32 + row) * 256 + sl * 4;
    f32x4 xv[8];
    float s = 0.f, s2 = 0.f;
#pragma unroll
    for (int i = 0; i < 8; ++i) {
      xv[i] = *(const f32x4*)(gr + i * 32);
#pragma unroll
      for (int j = 0; j < 4; ++j) { float f = xv[i][j]; s += f; s2 += f * f; }
    }
    s += __shfl_xor(s, 1, 64);  s += __shfl_xor(s, 2, 64);  s += __shfl_xor(s, 4, 64);
    s2 += __shfl_xor(s2, 1, 64); s2 += __shfl_xor(s2, 2, 64); s2 += __shfl_xor(s2, 4, 64);
    float mu = s * (1.f / 256.f);
    float var = s2 * (1.f / 256.f) - mu * mu;
    float istd = rsqrtf(var + EPSLN);
#pragma unroll
    for (int i = 0; i < 8; ++i) {
      int c = sl * 4 + i * 32;
      f32x4 g = *(const f32x4*)(lng + c);
      f32x4 b = *(const f32x4*)(lnb + c);
      *(unsigned long long*)(s_x + row * 264 + c) =
          pack4bf((xv[i][0] - mu) * istd * g[0] + b[0],
                  (xv[i][1] - mu) * istd * g[1] + b[1],
                  (xv[i][2] - mu) * istd * g[2] + b[2],
                  (xv[i][3] - mu) * istd * g[3] + b[3]);
    }
  }

  // V-pass: wave 0 also computes in-block softmax (4 threads per (pixel,head) row)
  if (kind == 1 && t < 64) {
    const int r = t >> 2, sl = t & 3;        // r = p*4 + m
    const int p = r >> 2, pix = qp0 + p;
    const float* ar = attg + (((size_t)pix) * 4 + (r & 3)) * 48 + sl * 12;
    float x[12];
#pragma unroll
    for (int i = 0; i < 3; ++i) {
      f32x4 v4 = *(const f32x4*)(ar + i * 4);
      x[i * 4] = v4[0]; x[i * 4 + 1] = v4[1]; x[i * 4 + 2] = v4[2]; x[i * 4 + 3] = v4[3];
    }
#pragma unroll
    for (int i = 0; i < 12; ++i) {
      int nn = (sl * 12 + i) >> 3;
      if (!mask[nn * QL + pix]) x[i] = -1e9f;
    }
    float mx = -3.0e38f;
#pragma unroll
    for (int i = 0; i < 12; ++i) mx = fmaxf(mx, x[i]);
    mx = fmaxf(mx, __shfl_xor(mx, 1, 64));
    mx = fmaxf(mx, __shfl_xor(mx, 2, 64));
    float sm = 0.f;
#pragma unroll
    for (int i = 0; i < 12; ++i) { float e = __expf(x[i] - mx); x[i] = e; sm += e; }
    sm += __shfl_xor(sm, 1, 64);
    sm += __shfl_xor(sm, 2, 64);
    float inv = 1.f / sm;
#pragma unroll
    for (int i = 0; i < 12; ++i) s_att[r * 48 + sl * 12 + i] = x[i] * inv;
  }
  __syncthreads();

  // MFMA: M=32, wave covers N-slice w*64
  const int lr = lane & 15, quad = lane >> 4;
  f32x4 acc[4][2];
  {
    f32x4 z = {0.f, 0.f, 0.f, 0.f};
#pragma unroll
    for (int a = 0; a < 4; ++a) { acc[a][0] = z; acc[a][1] = z; }
  }
  for (int kt = 0; kt < 8; ++kt) {
    bf16x8 xf[2];
    xf[0] = *(const bf16x8*)(s_x + lr * 264 + kt * 32 + quad * 8);
    xf[1] = *(const bf16x8*)(s_x + (16 + lr) * 264 + kt * 32 + quad * 8);
#pragma unroll
    for (int nt = 0; nt < 4; ++nt) {
      bf16x8 wf = *(const bf16x8*)(wTp + ((size_t)((w * 4 + nt) * 8 + kt) * 512 + lane * 8));
      acc[nt][0] = __builtin_amdgcn_mfma_f32_16x16x32_bf16(wf, xf[0], acc[nt][0], 0, 0, 0);
      acc[nt][1] = __builtin_amdgcn_mfma_f32_16x16x32_bf16(wf, xf[1], acc[nt][1], 0, 0, 0);
    }
  }
  __syncthreads();
#pragma unroll
  for (int nt = 0; nt < 4; ++nt) {
    int n0 = w * 64 + nt * 16 + quad * 4;
    f32x4 bb = *(const f32x4*)(bias + n0);
#pragma unroll
    for (int mt = 0; mt < 2; ++mt) {
      int m = mt * 16 + lr;
      f32x4 a = acc[nt][mt];
      *(unsigned long long*)(s_x + m * 264 + n0) =
          pack4bf(a[0] + bb[0], a[1] + bb[1], a[2] + bb[2], a[3] + bb[3]);
    }
  }
  __syncthreads();

  if (kind == 0) {
    // scores: all 256 threads, 2 lanes per 64-dot
    const int p = t >> 6, m = (t >> 4) & 3, g = (t >> 1) & 7, h = t & 1;
    const unsigned short* kr = s_x + (p * 8 + g) * 264 + m * 64 + h * 32;
    const unsigned short* qr = qh + ((size_t)n * QL + qp0 + p) * 256 + m * 64 + h * 32;
    float dot = 0.f;
#pragma unroll
    for (int i = 0; i < 4; ++i) {
      bf16x8 kv = *(const bf16x8*)(kr + i * 8);
      bf16x8 qv = *(const bf16x8*)(qr + i * 8);
#pragma unroll
      for (int j = 0; j < 8; ++j) dot += (float)kv[j] * (float)qv[j];
    }
    dot += __shfl_xor(dot, 1, 64);
    if (h == 0)
      attg[(((size_t)(qp0 + p)) * 4 + m) * 48 + n * 8 + g] = dot * SCALE;
  } else {
    const int p = t >> 6, c0 = (t & 63) * 4, m = c0 >> 6;
    const float* ar = s_att + (p * 4 + m) * 48 + n * 8;
    float aw[8];
#pragma unroll
    for (int j = 0; j < 8; ++j) aw[j] = ar[j];
    float o[4] = {0.f, 0.f, 0.f, 0.f};
#pragma unroll
    for (int g = 0; g < 8; ++g) {
      bf16x4 vv = *(const bf16x4*)(s_x + (p * 8 + g) * 264 + c0);
#pragma unroll
      for (int j = 0; j < 4; ++j) o[j] += aw[g] * (float)vv[j];
    }
    f32x4 ov = {o[0], o[1], o[2], o[3]};
    *(f32x4*)(opart + ((size_t)n * QL + qp0 + p) * 256 + c0) = ov;
  }
}

// ===== epilogue: MFMA proj + skip + LN + MLP + LN =========================
__global__ void __launch_bounds__(256)
epi_kernel(const float* __restrict__ opart, const float* __restrict__ skip,
           const unsigned short* __restrict__ wpp, const float* __restrict__ bp,
           const float* __restrict__ lng1, const float* __restrict__ lnb1,
           const unsigned short* __restrict__ w1p, const float* __restrict__ b1,
           const unsigned short* __restrict__ w2p, const float* __restrict__ b2,
           const float* __restrict__ lng2, const float* __restrict__ lnb2,
           float* __restrict__ out)
{
  __shared__ __align__(16) unsigned char smem[50688];
  unsigned short* s_a  = (unsigned short*)smem;            // 16*264 bf16
  float*          s_z  = (float*)(smem + 8448);            // 16*264 f32
  unsigned short* s_zb = (unsigned short*)(smem + 25344);  // 16*264 bf16
  unsigned short* s_h  = (unsigned short*)(smem + 33792);  // 16*528 bf16
  float*          s_z2 = (float*)(smem + 33792);           // alias over s_h
  const int t = threadIdx.x, q0 = blockIdx.x * 16;

  // a = sum_n opart[n], bf16-staged (float4 reads for MLP)
#pragma unroll
  for (int i = 0; i < 4; ++i) {
    int pos = i * 256 + t, p = pos >> 6, c4 = (pos & 63) * 4;
    const float* base = opart + (size_t)(q0 + p) * 256 + c4;
    f32x4 s = {0.f, 0.f, 0.f, 0.f};
#pragma unroll
    for (int nn = 0; nn < 6; ++nn) s += *(const f32x4*)(base + (size_t)nn * QL * 256);
    *(unsigned long long*)(s_a + p * 264 + c4) = pack4bf(s[0], s[1], s[2], s[3]);
  }
  __syncthreads();

  const int w = t >> 6, lane = t & 63, lr = lane & 15, quad = lane >> 4;

  // GEMM1: z = a @ wp + bp + skip
  {
    f32x4 acc[4];
    f32x4 z = {0.f, 0.f, 0.f, 0.f};
#pragma unroll
    for (int a = 0; a < 4; ++a) acc[a] = z;
    for (int kt = 0; kt < 8; ++kt) {
      bf16x8 xf = *(const bf16x8*)(s_a + lr * 264 + kt * 32 + quad * 8);
#pragma unroll
      for (int nt = 0; nt < 4; ++nt) {
        bf16x8 wf = *(const bf16x8*)(wpp + ((size_t)((w * 4 + nt) * 8 + kt) * 512 + lane * 8));
        acc[nt] = __builtin_amdgcn_mfma_f32_16x16x32_bf16(wf, xf, acc[nt], 0, 0, 0);
      }
    }
#pragma unroll
    for (int nt = 0; nt < 4; ++nt) {
      int n0 = w * 64 + nt * 16 + quad * 4;
      f32x4 bb = *(const f32x4*)(bp + n0);
      f32x4 sk;
#pragma unroll
      for (int j = 0; j < 4; ++j) sk[j] = skip[(size_t)(n0 + j) * QL + q0 + lr];
      *(f32x4*)(s_z + lr * 264 + n0) = acc[nt] + bb + sk;
    }
  }
  __syncthreads();

  // LN1
  {
    int r = t >> 4, l = t & 15;
    float s = 0.f, s2 = 0.f;
#pragma unroll
    for (int i = 0; i < 16; ++i) {
      float x = s_z[r * 264 + l + 16 * i];
      s += x; s2 += x * x;
    }
    s += __shfl_xor(s, 1, 64); s += __shfl_xor(s, 2, 64);
    s += __shfl_xor(s, 4, 64); s += __shfl_xor(s, 8, 64);
    s2 += __shfl_xor(s2, 1, 64); s2 += __shfl_xor(s2, 2, 64);
    s2 += __shfl_xor(s2, 4, 64); s2 += __shfl_xor(s2, 8, 64);
    float mu = s * (1.f / 256.f);
    float var = s2 * (1.f / 256.f) - mu * mu;
    float istd = rsqrtf(var + EPSLN);
#pragma unroll
    for (int i = 0; i < 16; ++i) {
      int d = l + 16 * i;
      float nv = (s_z[r * 264 + d] - mu) * istd * lng1[d] + lnb1[d];
      s_z[r * 264 + d] = nv;
      s_zb[r * 264 + d] = f2bf(nv);
    }
  }
  __syncthreads();

  // GEMM2: h = gelu(z @ w1 + b1), N=512
  {
    f32x4 acc[8];
    f32x4 z = {0.f, 0.f, 0.f, 0.f};
#pragma unroll
    for (int a = 0; a < 8; ++a) acc[a] = z;
    for (int kt = 0; kt < 8; ++kt) {
      bf16x8 xf = *(const bf16x8*)(s_zb + lr * 264 + kt * 32 + quad * 8);
#pragma unroll
      for (int nt = 0; nt < 8; ++nt) {
        bf16x8 wf = *(const bf16x8*)(w1p + ((size_t)((w * 8 + nt) * 8 + kt) * 512 + lane * 8));
        acc[nt] = __builtin_amdgcn_mfma_f32_16x16x32_bf16(wf, xf, acc[nt], 0, 0, 0);
      }
    }
#pragma unroll
    for (int nt = 0; nt < 8; ++nt) {
      int n0 = w * 128 + nt * 16 + quad * 4;
      f32x4 bb = *(const f32x4*)(b1 + n0);
      float hv[4];
#pragma unroll
      for (int j = 0; j < 4; ++j) {
        float val = acc[nt][j] + bb[j];
        hv[j] = 0.5f * val * (1.f + erff(val * 0.70710678118654752f));
      }
      *(unsigned long long*)(s_h + lr * 528 + n0) = pack4bf(hv[0], hv[1], hv[2], hv[3]);
    }
  }
  __syncthreads();

  // GEMM3: z2 = z + h @ w2 + b2 (K=512), result overlays s_h region
  {
    f32x4 acc[4];
    f32x4 z = {0.f, 0.f, 0.f, 0.f};
#pragma unroll
    for (int a = 0; a < 4; ++a) acc[a] = z;
    for (int kt = 0; kt < 16; ++kt) {
      bf16x8 xf = *(const bf16x8*)(s_h + lr * 528 + kt * 32 + quad * 8);
#pragma unroll
      for (int nt = 0; nt < 4; ++nt) {
        bf16x8 wf = *(const bf16x8*)(w2p + ((size_t)((w * 4 + nt) * 16 + kt) * 512 + lane * 8));
        acc[nt] = __builtin_amdgcn_mfma_f32_16x16x32_bf16(wf, xf, acc[nt], 0, 0, 0);
      }
    }
    f32x4 res[4];
#pragma unroll
    for (int nt = 0; nt < 4; ++nt) {
      int n0 = w * 64 + nt * 16 + quad * 4;
      f32x4 bb = *(const f32x4*)(b2 + n0);
      f32x4 zr = *(const f32x4*)(s_z + lr * 264 + n0);
      res[nt] = acc[nt] + bb + zr;
    }
    __syncthreads();   // all s_h reads done before overlay write
#pragma unroll
    for (int nt = 0; nt < 4; ++nt) {
      int n0 = w * 64 + nt * 16 + quad * 4;
      *(f32x4*)(s_z2 + lr * 264 + n0) = res[nt];
    }
  }
  __syncthreads();

  // LN2 in place
  {
    int r = t >> 4, l = t & 15;
    float s = 0.f, s2 = 0.f;
#pragma unroll
    for (int i = 0; i < 16; ++i) {
      float x = s_z2[r * 264 + l + 16 * i];
      s += x; s2 += x * x;
    }
    s += __shfl_xor(s, 1, 64); s += __shfl_xor(s, 2, 64);
    s += __shfl_xor(s, 4, 64); s += __shfl_xor(s, 8, 64);
    s2 += __shfl_xor(s2, 1, 64); s2 += __shfl_xor(s2, 2, 64);
    s2 += __shfl_xor(s2, 4, 64); s2 += __shfl_xor(s2, 8, 64);
    float mu = s * (1.f / 256.f);
    float var = s2 * (1.f / 256.f) - mu * mu;
    float istd = rsqrtf(var + EPSLN);
#pragma unroll
    for (int i = 0; i < 16; ++i) {
      int d = l + 16 * i;
      s_z2[r * 264 + d] = (s_z2[r * 264 + d] - mu) * istd * lng2[d] + lnb2[d];
    }
  }
  __syncthreads();

  // transposed store
#pragma unroll
  for (int i = 0; i < 16; ++i) {
    int c = i * 16 + (t >> 4), p = t & 15;
    out[(size_t)c * QL + q0 + p] = s_z2[p * 264 + c];
  }
}

extern "C" void kernel_launch(void* const* d_in, const int* in_sizes, int n_in,
                              void* d_out, int out_size, void* d_ws, size_t ws_size,
                              hipStream_t stream) {
  (void)in_sizes; (void)n_in; (void)out_size; (void)ws_size;
  const float* q     = (const float*)d_in[0];
  const float* k     = (const float*)d_in[1];
  const float* v     = (const float*)d_in[2];
  const float* skip  = (const float*)d_in[3];
  const int*   mask  = (const int*)d_in[4];
  const float* lnqg  = (const float*)d_in[5];
  const float* lnqb  = (const float*)d_in[6];
  const float* wq    = (const float*)d_in[7];
  const float* bq    = (const float*)d_in[8];
  const float* lnkg  = (const float*)d_in[9];
  const float* lnkb  = (const float*)d_in[10];
  const float* wk    = (const float*)d_in[11];
  const float* bk    = (const float*)d_in[12];
  const float* lnvg  = (const float*)d_in[13];
  const float* lnvb  = (const float*)d_in[14];
  const float* wv    = (const float*)d_in[15];
  const float* bv    = (const float*)d_in[16];
  const float* wp    = (const float*)d_in[17];
  const float* bp    = (const float*)d_in[18];
  const float* lng1  = (const float*)d_in[19];
  const float* lnb1  = (const float*)d_in[20];
  const float* w1    = (const float*)d_in[21];
  const float* b1    = (const float*)d_in[22];
  const float* w2    = (const float*)d_in[23];
  const float* b2    = (const float*)d_in[24];
  const float* lng2  = (const float*)d_in[25];
  const float* lnb2  = (const float*)d_in[26];
  float* out = (float*)d_out;

  unsigned char* ws = (unsigned char*)d_ws;
  unsigned short* wsu16 = (unsigned short*)d_ws;
  unsigned short* wqT = (unsigned short*)(ws + OFF_WQT);
  unsigned short* wkT = (unsigned short*)(ws + OFF_WKT);
  unsigned short* wvT = (unsigned short*)(ws + OFF_WVT);
  unsigned short* wpT = (unsigned short*)(ws + OFF_WPT);
  unsigned short* w1T = (unsigned short*)(ws + OFF_W1T);
  unsigned short* w2T = (unsigned short*)(ws + OFF_W2T);
  unsigned short* qh  = (unsigned short*)(ws + OFF_QH);
  float* attg  = (float*)(ws + OFF_ATT);
  float* opart = (float*)(ws + OFF_OPART);

  hipLaunchKernelGGL(prep_kernel, dim3(112), dim3(256), 0, stream,
                     wq, wk, wv, wp, w1, w2, wsu16);
  hipLaunchKernelGGL(projq_kernel, dim3(384), dim3(256), 0, stream,
                     q, lnqg, lnqb, wqT, bq, qh);
  hipLaunchKernelGGL(projkv_kernel, dim3(6144), dim3(256), 0, stream,
                     k, lnkg, lnkb, wkT, bk, qh, attg, mask, opart, 0);
  hipLaunchKernelGGL(projkv_kernel, dim3(6144), dim3(256), 0, stream,
                     v, lnvg, lnvb, wvT, bv, qh, attg, mask, opart, 1);
  hipLaunchKernelGGL(epi_kernel, dim3(QL / 16), dim3(256), 0, stream,
                     opart, skip, wpT, bp, lng1, lnb1, w1T, b1, w2T, b2, lng2, lnb2, out);
}

// Round 2
// 550.589 us; speedup vs baseline: 1.0436x; 1.0092x over previous
//
#include <hip/hip_runtime.h>
#include <hip/hip_bf16.h>
#include <math.h>

#define NF 6
#define QL 4096
#define SCALE 0.125f
#define EPSLN 1e-5f

typedef __bf16 bf16x8 __attribute__((ext_vector_type(8)));
typedef __bf16 bf16x4 __attribute__((ext_vector_type(4)));
typedef float  f32x4  __attribute__((ext_vector_type(4)));

// ---- workspace layout (bytes) ----
#define OFF_WQT   0u
#define OFF_WKT   131072u
#define OFF_WVT   262144u
#define OFF_WPT   393216u
#define OFF_W1T   524288u     // 512x256 packed bf16
#define OFF_W2T   786432u     // 256x512 packed bf16
#define OFF_QH    1048576u    // 24576 x 256 bf16
#define OFF_ATT   13631488u   // 4096 x 256 f32 (final per-pixel attn output)

__device__ __forceinline__ unsigned short f2bf(float x) {
  union { float f; unsigned u; } v; v.f = x;
  unsigned r = v.u + 0x7FFFu + ((v.u >> 16) & 1u);
  return (unsigned short)(r >> 16);
}
__device__ __forceinline__ unsigned long long pack4bf(float a, float b, float c, float d) {
  unsigned d0 = (unsigned)f2bf(a) | ((unsigned)f2bf(b) << 16);
  unsigned d1 = (unsigned)f2bf(c) | ((unsigned)f2bf(d) << 16);
  return (unsigned long long)d0 | ((unsigned long long)d1 << 32);
}

// ===== prep: W[K][N] f32 -> MFMA-fragment-packed bf16 =====================
// layout: out[(ntile*KT + kt)*512 + lane*8 + j] = W[kt*32 + (lane>>4)*8 + j][ntile*16 + (lane&15)]
__global__ void __launch_bounds__(256)
prep_kernel(const float* __restrict__ wq, const float* __restrict__ wk,
            const float* __restrict__ wv, const float* __restrict__ wp,
            const float* __restrict__ w1, const float* __restrict__ w2,
            unsigned short* __restrict__ wsu16)
{
  const int blk = blockIdx.x, t = threadIdx.x;
  const float* src; unsigned short* dst; int N, KT, ntile;
  if (blk < 64) {
    int mi = blk >> 4; ntile = blk & 15; N = 256; KT = 8;
    src = (mi == 0) ? wq : (mi == 1) ? wk : (mi == 2) ? wv : wp;
    dst = wsu16 + (size_t)mi * 65536;
  } else if (blk < 96) {
    ntile = blk - 64; N = 512; KT = 8; src = w1; dst = wsu16 + OFF_W1T / 2;
  } else {
    ntile = blk - 96; N = 256; KT = 16; src = w2; dst = wsu16 + OFF_W2T / 2;
  }
  const int lane = t & 63;
  const int lr = lane & 15, quad = lane >> 4;
  const int ncol = ntile * 16 + lr;
  for (int kt = (t >> 6); kt < KT; kt += 4) {
    unsigned v8[8];
#pragma unroll
    for (int j = 0; j < 8; ++j) {
      int krow = kt * 32 + quad * 8 + j;
      v8[j] = f2bf(src[(size_t)krow * N + ncol]);
    }
    uint4 u;
    u.x = v8[0] | (v8[1] << 16); u.y = v8[2] | (v8[3] << 16);
    u.z = v8[4] | (v8[5] << 16); u.w = v8[6] | (v8[7] << 16);
    *(uint4*)(dst + ((size_t)(ntile * KT + kt) * 512 + lane * 8)) = u;
  }
}

// ===== proj-q: gather-transpose + LN + MFMA (64-px tiles) -> qh bf16 ======
__global__ void __launch_bounds__(256, 4)
projq_kernel(const float* __restrict__ src,
             const float* __restrict__ lng, const float* __restrict__ lnb,
             const unsigned short* __restrict__ wTp,
             const float* __restrict__ bias,
             unsigned short* __restrict__ qh)
{
  __shared__ __align__(16) unsigned short s_x[64 * 264];
  const int t = threadIdx.x, blk = blockIdx.x;
  const int n = blk >> 6, qp0 = (blk & 63) << 6;

  // stage + transpose raw as bf16
  {
    const int l16 = t & 15, dg = t >> 4;
    for (int it = 0; it < 16; ++it) {
      int dcol = it * 16 + dg;
      float4 x = *(const float4*)(src + ((size_t)(n * 256 + dcol)) * 4096 + qp0 + l16 * 4);
      s_x[(l16 * 4 + 0) * 264 + dcol] = f2bf(x.x);
      s_x[(l16 * 4 + 1) * 264 + dcol] = f2bf(x.y);
      s_x[(l16 * 4 + 2) * 264 + dcol] = f2bf(x.z);
      s_x[(l16 * 4 + 3) * 264 + dcol] = f2bf(x.w);
    }
  }
  __syncthreads();
  // two-pass LN (4 threads/row)
  {
    const int row = t >> 2, sl = t & 3;
    float s = 0.f, s2 = 0.f;
#pragma unroll
    for (int i = 0; i < 8; ++i) {
      bf16x8 xv = *(const bf16x8*)(s_x + row * 264 + (i * 4 + sl) * 8);
#pragma unroll
      for (int j = 0; j < 8; ++j) { float f = (float)xv[j]; s += f; s2 += f * f; }
    }
    s += __shfl_xor(s, 1, 64);  s += __shfl_xor(s, 2, 64);
    s2 += __shfl_xor(s2, 1, 64); s2 += __shfl_xor(s2, 2, 64);
    float mu = s * (1.f / 256.f);
    float var = s2 * (1.f / 256.f) - mu * mu;
    float istd = rsqrtf(var + EPSLN);
#pragma unroll
    for (int i = 0; i < 8; ++i) {
      int c = (i * 4 + sl) * 8;
      bf16x8 xv = *(const bf16x8*)(s_x + row * 264 + c);
      f32x4 ga = *(const f32x4*)(lng + c), gb = *(const f32x4*)(lng + c + 4);
      f32x4 ba = *(const f32x4*)(lnb + c), bb = *(const f32x4*)(lnb + c + 4);
      uint4 u;
      u.x = (unsigned)f2bf(((float)xv[0] - mu) * istd * ga[0] + ba[0]) |
            ((unsigned)f2bf(((float)xv[1] - mu) * istd * ga[1] + ba[1]) << 16);
      u.y = (unsigned)f2bf(((float)xv[2] - mu) * istd * ga[2] + ba[2]) |
            ((unsigned)f2bf(((float)xv[3] - mu) * istd * ga[3] + ba[3]) << 16);
      u.z = (unsigned)f2bf(((float)xv[4] - mu) * istd * gb[0] + bb[0]) |
            ((unsigned)f2bf(((float)xv[5] - mu) * istd * gb[1] + bb[1]) << 16);
      u.w = (unsigned)f2bf(((float)xv[6] - mu) * istd * gb[2] + bb[2]) |
            ((unsigned)f2bf(((float)xv[7] - mu) * istd * gb[3] + bb[3]) << 16);
      *(uint4*)(s_x + row * 264 + c) = u;
    }
  }
  __syncthreads();

  // MFMA: M=64, wave covers N-slice w*64
  const int w = t >> 6, lane = t & 63, lr = lane & 15, quad = lane >> 4;
  f32x4 acc[4][4];
  {
    f32x4 z = {0.f, 0.f, 0.f, 0.f};
#pragma unroll
    for (int a = 0; a < 4; ++a)
#pragma unroll
      for (int b = 0; b < 4; ++b) acc[a][b] = z;
  }
  for (int kt = 0; kt < 8; ++kt) {
    bf16x8 xf[4];
#pragma unroll
    for (int mt = 0; mt < 4; ++mt)
      xf[mt] = *(const bf16x8*)(s_x + (mt * 16 + lr) * 264 + kt * 32 + quad * 8);
#pragma unroll
    for (int nt = 0; nt < 4; ++nt) {
      bf16x8 wf = *(const bf16x8*)(wTp + ((size_t)((w * 4 + nt) * 8 + kt) * 512 + lane * 8));
#pragma unroll
      for (int mt = 0; mt < 4; ++mt)
        acc[nt][mt] = __builtin_amdgcn_mfma_f32_16x16x32_bf16(wf, xf[mt], acc[nt][mt], 0, 0, 0);
    }
  }
  __syncthreads();
#pragma unroll
  for (int nt = 0; nt < 4; ++nt) {
    int n0 = w * 64 + nt * 16 + quad * 4;
    f32x4 bb = *(const f32x4*)(bias + n0);
#pragma unroll
    for (int mt = 0; mt < 4; ++mt) {
      int m = mt * 16 + lr;
      f32x4 a = acc[nt][mt];
      *(unsigned long long*)(s_x + m * 264 + n0) =
          pack4bf(a[0] + bb[0], a[1] + bb[1], a[2] + bb[2], a[3] + bb[3]);
    }
  }
  __syncthreads();
  // dump 64 rows x 512B contiguous
  unsigned char* ob = (unsigned char*)qh + ((size_t)n * QL + qp0) * 512;
#pragma unroll
  for (int i = 0; i < 8; ++i) {
    int lin = i * 4096 + t * 16;
    int r = lin >> 9, off = lin & 511;
    *(uint4*)(ob + lin) = *(const uint4*)((const unsigned char*)s_x + r * 528 + off);
  }
}

// ---- stage 256-f32 rows from global, LayerNorm, write bf16 to LDS --------
// rows row0..row0+nrows-1 of this pixel's (n,g) bundle; 8 threads per row.
__device__ __forceinline__ void stage_ln_rows(
    const float* __restrict__ src, int p, int row0, int nrows,
    const float* __restrict__ lng, const float* __restrict__ lnb,
    unsigned short* __restrict__ s_x, int t)
{
  const int rel = t >> 3;
  if (rel < nrows) {
    const int row = row0 + rel, sl = t & 7;
    const int n = row >> 3, g = row & 7;
    const float* gr = src + ((size_t)((n * 4096 + p) * 8 + g)) * 256 + sl * 4;
    f32x4 xv[8];
    float s = 0.f, s2 = 0.f;
#pragma unroll
    for (int i = 0; i < 8; ++i) {
      xv[i] = *(const f32x4*)(gr + i * 32);
#pragma unroll
      for (int j = 0; j < 4; ++j) { float f = xv[i][j]; s += f; s2 += f * f; }
    }
    s += __shfl_xor(s, 1, 64);  s += __shfl_xor(s, 2, 64);  s += __shfl_xor(s, 4, 64);
    s2 += __shfl_xor(s2, 1, 64); s2 += __shfl_xor(s2, 2, 64); s2 += __shfl_xor(s2, 4, 64);
    float mu = s * (1.f / 256.f);
    float var = s2 * (1.f / 256.f) - mu * mu;
    float istd = rsqrtf(var + EPSLN);
#pragma unroll
    for (int i = 0; i < 8; ++i) {
      int c = sl * 4 + i * 32;
      f32x4 g4 = *(const f32x4*)(lng + c);
      f32x4 b4 = *(const f32x4*)(lnb + c);
      *(unsigned long long*)(s_x + row * 264 + c) =
          pack4bf((xv[i][0] - mu) * istd * g4[0] + b4[0],
                  (xv[i][1] - mu) * istd * g4[1] + b4[1],
                  (xv[i][2] - mu) * istd * g4[2] + b4[2],
                  (xv[i][3] - mu) * istd * g4[3] + b4[3]);
    }
  }
}

// ===== fused attention middle: one block per pixel ========================
// block owns 48 K-rows and 48 V-rows (6 frames x 8 groups) of its pixel:
// LN+project K -> scores vs qh -> softmax(all 48 keys, masked) -> LN+project V
// -> PV -> final per-pixel attn output (4096 x 256 f32).
__global__ void __launch_bounds__(256, 4)
fused_attn_kernel(const float* __restrict__ ksrc, const float* __restrict__ vsrc,
                  const float* __restrict__ lnkg, const float* __restrict__ lnkb,
                  const unsigned short* __restrict__ wkT, const float* __restrict__ bk,
                  const float* __restrict__ lnvg, const float* __restrict__ lnvb,
                  const unsigned short* __restrict__ wvT, const float* __restrict__ bv,
                  const unsigned short* __restrict__ qh,
                  const int* __restrict__ mask,
                  float* __restrict__ att_out)
{
  __shared__ __align__(16) unsigned short s_x[48 * 264];  // staged rows / projections
  __shared__ __align__(16) unsigned short s_q[6 * 264];   // qh rows for this pixel
  __shared__ __align__(16) float s_att[4 * 48];           // scores -> probs
  const int t = threadIdx.x, p = blockIdx.x;
  const int w = t >> 6, lane = t & 63, lr = lane & 15, quad = lane >> 4;

  // stage qh rows (6 x 512B) + K rows with LN
  if (t < 192) {
    int n = t >> 5, c8 = (t & 31) * 8;
    *(uint4*)(s_q + n * 264 + c8) = *(const uint4*)(qh + ((size_t)(n * QL + p)) * 256 + c8);
  }
  stage_ln_rows(ksrc, p, 0, 32, lnkg, lnkb, s_x, t);
  stage_ln_rows(ksrc, p, 32, 16, lnkg, lnkb, s_x, t);
  __syncthreads();

  // ---- project K: M=48, wave w covers N-slice w*64 ----
  {
    f32x4 acc[4][3];
    {
      f32x4 z = {0.f, 0.f, 0.f, 0.f};
#pragma unroll
      for (int a = 0; a < 4; ++a)
#pragma unroll
        for (int b = 0; b < 3; ++b) acc[a][b] = z;
    }
    for (int kt = 0; kt < 8; ++kt) {
      bf16x8 xf[3];
#pragma unroll
      for (int mt = 0; mt < 3; ++mt)
        xf[mt] = *(const bf16x8*)(s_x + (mt * 16 + lr) * 264 + kt * 32 + quad * 8);
#pragma unroll
      for (int nt = 0; nt < 4; ++nt) {
        bf16x8 wf = *(const bf16x8*)(wkT + ((size_t)((w * 4 + nt) * 8 + kt) * 512 + lane * 8));
#pragma unroll
        for (int mt = 0; mt < 3; ++mt)
          acc[nt][mt] = __builtin_amdgcn_mfma_f32_16x16x32_bf16(wf, xf[mt], acc[nt][mt], 0, 0, 0);
      }
    }
    __syncthreads();
#pragma unroll
    for (int nt = 0; nt < 4; ++nt) {
      int n0 = w * 64 + nt * 16 + quad * 4;
      f32x4 bb = *(const f32x4*)(bk + n0);
#pragma unroll
      for (int mt = 0; mt < 3; ++mt) {
        int m = mt * 16 + lr;
        f32x4 a = acc[nt][mt];
        *(unsigned long long*)(s_x + m * 264 + n0) =
            pack4bf(a[0] + bb[0], a[1] + bb[1], a[2] + bb[2], a[3] + bb[3]);
      }
    }
  }
  __syncthreads();

  // ---- scores: 4 heads x 48 keys, 64-dim dots (all LDS) ----
  if (t < 192) {
    const int m = t / 48, key = t % 48;
    const unsigned short* kr = s_x + key * 264 + m * 64;
    const unsigned short* qr = s_q + (key >> 3) * 264 + m * 64;
    float dot = 0.f;
#pragma unroll
    for (int i = 0; i < 8; ++i) {
      bf16x8 kv = *(const bf16x8*)(kr + i * 8);
      bf16x8 qv = *(const bf16x8*)(qr + i * 8);
#pragma unroll
      for (int j = 0; j < 8; ++j) dot += (float)kv[j] * (float)qv[j];
    }
    s_att[m * 48 + key] = dot * SCALE;
  }
  __syncthreads();

  // ---- stage+LN V (overwrites s_x) while wave0 lane-group does softmax ----
  stage_ln_rows(vsrc, p, 0, 32, lnvg, lnvb, s_x, t);
  stage_ln_rows(vsrc, p, 32, 16, lnvg, lnvb, s_x, t);
  if (t < 16) {
    const int r = t >> 2, sl = t & 3;
    float x[12];
#pragma unroll
    for (int j = 0; j < 12; ++j) {
      int key = sl * 12 + j;
      float v = s_att[r * 48 + key];
      x[j] = mask[(key >> 3) * QL + p] ? v : -1e9f;
    }
    float mx = -3.0e38f;
#pragma unroll
    for (int j = 0; j < 12; ++j) mx = fmaxf(mx, x[j]);
    mx = fmaxf(mx, __shfl_xor(mx, 1, 64));
    mx = fmaxf(mx, __shfl_xor(mx, 2, 64));
    float sm = 0.f;
#pragma unroll
    for (int j = 0; j < 12; ++j) { float e = __expf(x[j] - mx); x[j] = e; sm += e; }
    sm += __shfl_xor(sm, 1, 64);
    sm += __shfl_xor(sm, 2, 64);
    float inv = 1.f / sm;
#pragma unroll
    for (int j = 0; j < 12; ++j) s_att[r * 48 + sl * 12 + j] = x[j] * inv;
  }
  __syncthreads();

  // ---- project V ----
  {
    f32x4 acc[4][3];
    {
      f32x4 z = {0.f, 0.f, 0.f, 0.f};
#pragma unroll
      for (int a = 0; a < 4; ++a)
#pragma unroll
        for (int b = 0; b < 3; ++b) acc[a][b] = z;
    }
    for (int kt = 0; kt < 8; ++kt) {
      bf16x8 xf[3];
#pragma unroll
      for (int mt = 0; mt < 3; ++mt)
        xf[mt] = *(const bf16x8*)(s_x + (mt * 16 + lr) * 264 + kt * 32 + quad * 8);
#pragma unroll
      for (int nt = 0; nt < 4; ++nt) {
        bf16x8 wf = *(const bf16x8*)(wvT + ((size_t)((w * 4 + nt) * 8 + kt) * 512 + lane * 8));
#pragma unroll
        for (int mt = 0; mt < 3; ++mt)
          acc[nt][mt] = __builtin_amdgcn_mfma_f32_16x16x32_bf16(wf, xf[mt], acc[nt][mt], 0, 0, 0);
      }
    }
    __syncthreads();
#pragma unroll
    for (int nt = 0; nt < 4; ++nt) {
      int n0 = w * 64 + nt * 16 + quad * 4;
      f32x4 bb = *(const f32x4*)(bv + n0);
#pragma unroll
      for (int mt = 0; mt < 3; ++mt) {
        int m = mt * 16 + lr;
        f32x4 a = acc[nt][mt];
        *(unsigned long long*)(s_x + m * 264 + n0) =
            pack4bf(a[0] + bb[0], a[1] + bb[1], a[2] + bb[2], a[3] + bb[3]);
      }
    }
  }
  __syncthreads();

  // ---- PV: 64 col-quads x 4 key-slices(12 keys) -> reduce -> global ----
  {
    const int cq = t >> 2, ks = t & 3, m = cq >> 4;
    float aw[12];
#pragma unroll
    for (int j = 0; j < 12; ++j) aw[j] = s_att[m * 48 + ks * 12 + j];
    float o[4] = {0.f, 0.f, 0.f, 0.f};
#pragma unroll
    for (int j = 0; j < 12; ++j) {
      bf16x4 vv = *(const bf16x4*)(s_x + (ks * 12 + j) * 264 + cq * 4);
#pragma unroll
      for (int c = 0; c < 4; ++c) o[c] += aw[j] * (float)vv[c];
    }
#pragma unroll
    for (int c = 0; c < 4; ++c) {
      o[c] += __shfl_xor(o[c], 1, 64);
      o[c] += __shfl_xor(o[c], 2, 64);
    }
    if (ks == 0) {
      f32x4 ov = {o[0], o[1], o[2], o[3]};
      *(f32x4*)(att_out + (size_t)p * 256 + cq * 4) = ov;
    }
  }
}

// ===== epilogue: MFMA proj + skip + LN + MLP + LN =========================
__global__ void __launch_bounds__(256)
epi_kernel(const float* __restrict__ att_in, const float* __restrict__ skip,
           const unsigned short* __restrict__ wpp, const float* __restrict__ bp,
           const float* __restrict__ lng1, const float* __restrict__ lnb1,
           const unsigned short* __restrict__ w1p, const float* __restrict__ b1,
           const unsigned short* __restrict__ w2p, const float* __restrict__ b2,
           const float* __restrict__ lng2, const float* __restrict__ lnb2,
           float* __restrict__ out)
{
  __shared__ __align__(16) unsigned char smem[50688];
  unsigned short* s_a  = (unsigned short*)smem;            // 16*264 bf16
  float*          s_z  = (float*)(smem + 8448);            // 16*264 f32
  unsigned short* s_zb = (unsigned short*)(smem + 25344);  // 16*264 bf16
  unsigned short* s_h  = (unsigned short*)(smem + 33792);  // 16*528 bf16
  float*          s_z2 = (float*)(smem + 33792);           // alias over s_h
  const int t = threadIdx.x, q0 = blockIdx.x * 16;

  // load a (final attn output), bf16-stage
#pragma unroll
  for (int i = 0; i < 4; ++i) {
    int pos = i * 256 + t, p = pos >> 6, c4 = (pos & 63) * 4;
    f32x4 s = *(const f32x4*)(att_in + (size_t)(q0 + p) * 256 + c4);
    *(unsigned long long*)(s_a + p * 264 + c4) = pack4bf(s[0], s[1], s[2], s[3]);
  }
  __syncthreads();

  const int w = t >> 6, lane = t & 63, lr = lane & 15, quad = lane >> 4;

  // GEMM1: z = a @ wp + bp + skip
  {
    f32x4 acc[4];
    f32x4 z = {0.f, 0.f, 0.f, 0.f};
#pragma unroll
    for (int a = 0; a < 4; ++a) acc[a] = z;
    for (int kt = 0; kt < 8; ++kt) {
      bf16x8 xf = *(const bf16x8*)(s_a + lr * 264 + kt * 32 + quad * 8);
#pragma unroll
      for (int nt = 0; nt < 4; ++nt) {
        bf16x8 wf = *(const bf16x8*)(wpp + ((size_t)((w * 4 + nt) * 8 + kt) * 512 + lane * 8));
        acc[nt] = __builtin_amdgcn_mfma_f32_16x16x32_bf16(wf, xf, acc[nt], 0, 0, 0);
      }
    }
#pragma unroll
    for (int nt = 0; nt < 4; ++nt) {
      int n0 = w * 64 + nt * 16 + quad * 4;
      f32x4 bb = *(const f32x4*)(bp + n0);
      f32x4 sk;
#pragma unroll
      for (int j = 0; j < 4; ++j) sk[j] = skip[(size_t)(n0 + j) * QL + q0 + lr];
      *(f32x4*)(s_z + lr * 264 + n0) = acc[nt] + bb + sk;
    }
  }
  __syncthreads();

  // LN1
  {
    int r = t >> 4, l = t & 15;
    float s = 0.f, s2 = 0.f;
#pragma unroll
    for (int i = 0; i < 16; ++i) {
      float x = s_z[r * 264 + l + 16 * i];
      s += x; s2 += x * x;
    }
    s += __shfl_xor(s, 1, 64); s += __shfl_xor(s, 2, 64);
    s += __shfl_xor(s, 4, 64); s += __shfl_xor(s, 8, 64);
    s2 += __shfl_xor(s2, 1, 64); s2 += __shfl_xor(s2, 2, 64);
    s2 += __shfl_xor(s2, 4, 64); s2 += __shfl_xor(s2, 8, 64);
    float mu = s * (1.f / 256.f);
    float var = s2 * (1.f / 256.f) - mu * mu;
    float istd = rsqrtf(var + EPSLN);
#pragma unroll
    for (int i = 0; i < 16; ++i) {
      int d = l + 16 * i;
      float nv = (s_z[r * 264 + d] - mu) * istd * lng1[d] + lnb1[d];
      s_z[r * 264 + d] = nv;
      s_zb[r * 264 + d] = f2bf(nv);
    }
  }
  __syncthreads();

  // GEMM2: h = gelu(z @ w1 + b1), N=512
  {
    f32x4 acc[8];
    f32x4 z = {0.f, 0.f, 0.f, 0.f};
#pragma unroll
    for (int a = 0; a < 8; ++a) acc[a] = z;
    for (int kt = 0; kt < 8; ++kt) {
      bf16x8 xf = *(const bf16x8*)(s_zb + lr * 264 + kt * 32 + quad * 8);
#pragma unroll
      for (int nt = 0; nt < 8; ++nt) {
        bf16x8 wf = *(const bf16x8*)(w1p + ((size_t)((w * 8 + nt) * 8 + kt) * 512 + lane * 8));
        acc[nt] = __builtin_amdgcn_mfma_f32_16x16x32_bf16(wf, xf, acc[nt], 0, 0, 0);
      }
    }
#pragma unroll
    for (int nt = 0; nt < 8; ++nt) {
      int n0 = w * 128 + nt * 16 + quad * 4;
      f32x4 bb = *(const f32x4*)(b1 + n0);
      float hv[4];
#pragma unroll
      for (int j = 0; j < 4; ++j) {
        float val = acc[nt][j] + bb[j];
        hv[j] = 0.5f * val * (1.f + erff(val * 0.70710678118654752f));
      }
      *(unsigned long long*)(s_h + lr * 528 + n0) = pack4bf(hv[0], hv[1], hv[2], hv[3]);
    }
  }
  __syncthreads();

  // GEMM3: z2 = z + h @ w2 + b2 (K=512), result overlays s_h region
  {
    f32x4 acc[4];
    f32x4 z = {0.f, 0.f, 0.f, 0.f};
#pragma unroll
    for (int a = 0; a < 4; ++a) acc[a] = z;
    for (int kt = 0; kt < 16; ++kt) {
      bf16x8 xf = *(const bf16x8*)(s_h + lr * 528 + kt * 32 + quad * 8);
#pragma unroll
      for (int nt = 0; nt < 4; ++nt) {
        bf16x8 wf = *(const bf16x8*)(w2p + ((size_t)((w * 4 + nt) * 16 + kt) * 512 + lane * 8));
        acc[nt] = __builtin_amdgcn_mfma_f32_16x16x32_bf16(wf, xf, acc[nt], 0, 0, 0);
      }
    }
    f32x4 res[4];
#pragma unroll
    for (int nt = 0; nt < 4; ++nt) {
      int n0 = w * 64 + nt * 16 + quad * 4;
      f32x4 bb = *(const f32x4*)(b2 + n0);
      f32x4 zr = *(const f32x4*)(s_z + lr * 264 + n0);
      res[nt] = acc[nt] + bb + zr;
    }
    __syncthreads();   // all s_h reads done before overlay write
#pragma unroll
    for (int nt = 0; nt < 4; ++nt) {
      int n0 = w * 64 + nt * 16 + quad * 4;
      *(f32x4*)(s_z2 + lr * 264 + n0) = res[nt];
    }
  }
  __syncthreads();

  // LN2 in place
  {
    int r = t >> 4, l = t & 15;
    float s = 0.f, s2 = 0.f;
#pragma unroll
    for (int i = 0; i < 16; ++i) {
      float x = s_z2[r * 264 + l + 16 * i];
      s += x; s2 += x * x;
    }
    s += __shfl_xor(s, 1, 64); s += __shfl_xor(s, 2, 64);
    s += __shfl_xor(s, 4, 64); s += __shfl_xor(s, 8, 64);
    s2 += __shfl_xor(s2, 1, 64); s2 += __shfl_xor(s2, 2, 64);
    s2 += __shfl_xor(s2, 4, 64); s2 += __shfl_xor(s2, 8, 64);
    float mu = s * (1.f / 256.f);
    float var = s2 * (1.f / 256.f) - mu * mu;
    float istd = rsqrtf(var + EPSLN);
#pragma unroll
    for (int i = 0; i < 16; ++i) {
      int d = l + 16 * i;
      s_z2[r * 264 + d] = (s_z2[r * 264 + d] - mu) * istd * lng2[d] + lnb2[d];
    }
  }
  __syncthreads();

  // transposed store
#pragma unroll
  for (int i = 0; i < 16; ++i) {
    int c = i * 16 + (t >> 4), p = t & 15;
    out[(size_t)c * QL + q0 + p] = s_z2[p * 264 + c];
  }
}

extern "C" void kernel_launch(void* const* d_in, const int* in_sizes, int n_in,
                              void* d_out, int out_size, void* d_ws, size_t ws_size,
                              hipStream_t stream) {
  (void)in_sizes; (void)n_in; (void)out_size; (void)ws_size;
  const float* q     = (const float*)d_in[0];
  const float* k     = (const float*)d_in[1];
  const float* v     = (const float*)d_in[2];
  const float* skip  = (const float*)d_in[3];
  const int*   mask  = (const int*)d_in[4];
  const float* lnqg  = (const float*)d_in[5];
  const float* lnqb  = (const float*)d_in[6];
  const float* wq    = (const float*)d_in[7];
  const float* bq    = (const float*)d_in[8];
  const float* lnkg  = (const float*)d_in[9];
  const float* lnkb  = (const float*)d_in[10];
  const float* wk    = (const float*)d_in[11];
  const float* bk    = (const float*)d_in[12];
  const float* lnvg  = (const float*)d_in[13];
  const float* lnvb  = (const float*)d_in[14];
  const float* wv    = (const float*)d_in[15];
  const float* bv    = (const float*)d_in[16];
  const float* wp    = (const float*)d_in[17];
  const float* bp    = (const float*)d_in[18];
  const float* lng1  = (const float*)d_in[19];
  const float* lnb1  = (const float*)d_in[20];
  const float* w1    = (const float*)d_in[21];
  const float* b1    = (const float*)d_in[22];
  const float* w2    = (const float*)d_in[23];
  const float* b2    = (const float*)d_in[24];
  const float* lng2  = (const float*)d_in[25];
  const float* lnb2  = (const float*)d_in[26];
  float* out = (float*)d_out;

  unsigned char* ws = (unsigned char*)d_ws;
  unsigned short* wsu16 = (unsigned short*)d_ws;
  unsigned short* wqT = (unsigned short*)(ws + OFF_WQT);
  unsigned short* wkT = (unsigned short*)(ws + OFF_WKT);
  unsigned short* wvT = (unsigned short*)(ws + OFF_WVT);
  unsigned short* wpT = (unsigned short*)(ws + OFF_WPT);
  unsigned short* w1T = (unsigned short*)(ws + OFF_W1T);
  unsigned short* w2T = (unsigned short*)(ws + OFF_W2T);
  unsigned short* qh  = (unsigned short*)(ws + OFF_QH);
  float* att_out = (float*)(ws + OFF_ATT);

  hipLaunchKernelGGL(prep_kernel, dim3(112), dim3(256), 0, stream,
                     wq, wk, wv, wp, w1, w2, wsu16);
  hipLaunchKernelGGL(projq_kernel, dim3(384), dim3(256), 0, stream,
                     q, lnqg, lnqb, wqT, bq, qh);
  hipLaunchKernelGGL(fused_attn_kernel, dim3(QL), dim3(256), 0, stream,
                     k, v, lnkg, lnkb, wkT, bk, lnvg, lnvb, wvT, bv, qh, mask, att_out);
  hipLaunchKernelGGL(epi_kernel, dim3(QL / 16), dim3(256), 0, stream,
                     att_out, skip, wpT, bp, lng1, lnb1, w1T, b1, w2T, b2, lng2, lnb2, out);
}